// Round 1
// 2249.763 us; speedup vs baseline: 1.1996x; 1.1996x over previous
//
#include <hip/hip_runtime.h>

#define T_SEQ 512
#define NB    256
#define NIN   248
#define NH    1024

typedef __attribute__((ext_vector_type(8))) short          short8;
typedef __attribute__((ext_vector_type(4))) float          f32x4;
typedef __attribute__((ext_vector_type(4))) unsigned int   uint4v;
typedef __attribute__((ext_vector_type(4))) float          float4v;
typedef unsigned long long u64;

#define AS_RELAXED __ATOMIC_RELAXED
#define AS_AGENT   __HIP_MEMORY_SCOPE_AGENT

__device__ __forceinline__ unsigned short f2bf(float f){
  unsigned int u = __float_as_uint(f);
  u += 0x7FFFu + ((u >> 16) & 1u);     // RNE
  return (unsigned short)(u >> 16);
}

__device__ __forceinline__ float tanh_fast(float v){
  float e = __expf(2.0f * v);          // overflow -> inf -> tanh -> 1 (safe)
  return 1.0f - 2.0f / (e + 1.0f);
}

// Persistent kernel, plain launch. 256 WGs = 16 batch-groups (bg) x 16
// hidden-groups (jg); all blocks co-resident (1 block/CU).
//
// R-new: the per-bg counter barrier (16 serialized fetch_adds on one line +
// spin-detect + extra __syncthreads) is replaced by a per-producer FLAG
// array: flags[bg][jg] = 1 + (latest h index produced by jg). Arrival is a
// single relaxed atomic store; consumers poll all 16 flags with ONE vector
// load (lanes 0..15), per wave, no extra workgroup barrier. Skew between
// WGs now pipelines instead of being paid as a full barrier round.
//
// Ping-pong safety without a full barrier: WG X stores its h[t+2] chunk
// (overwriting the h[t] buffer) only after its step-(t+1) poll observed
// flags[*] >= t+2, i.e. every peer finished step t and therefore finished
// READING h[t] (their P1 reads precede their flag store by two
// __syncthreads). So no consumer of h[t] can still be reading it.
//
// Ordering: data stores are relaxed agent-scope atomics (write-through,
// acked at the coherence point); the pre-flag __syncthreads drains
// vmcnt(0) for ALL threads' stores, then tid0 stores the flag. A consumer
// observing the flag therefore observes the data via the same coherence
// point. (Identical argument to the previous counter-barrier version.)
__launch_bounds__(256, 1)
__global__ void rnn_scan_kernel(const float* __restrict__ x,
                                const float* __restrict__ W_ih,
                                const float* __restrict__ b_ih,
                                const float* __restrict__ W_hh,
                                const float* __restrict__ b_hh,
                                const float* __restrict__ W_out,
                                unsigned short* __restrict__ hbuf,
                                float* __restrict__ z,
                                unsigned int* __restrict__ bar)
{
  __shared__ alignas(16) unsigned short h_frag[2048 * 8]; // 32 KB A-fragments
  __shared__ alignas(16) unsigned short x_frag[512 * 8];  //  8 KB x-fragments
  __shared__ alignas(8)  unsigned short h_out[16 * 64];   //  2 KB store-transpose
  __shared__ float z_hist[T_SEQ * 16];                    // 32 KB deferred z partials

  const int tid    = threadIdx.x;
  const int wg     = blockIdx.x;
  const int r16    = wg & 15;
  const int bg     = (r16 & 7) * 2 + (r16 >> 3);  // same-XCD grouping heuristic
  const int jg     = wg >> 4;
  const int b_base = bg * 16;
  const int l      = tid & 63;
  const int wv     = tid >> 6;
  const int n      = l & 15;     // MFMA col (B-operand n / C-D col)
  const int quad   = l >> 4;
  const int j      = jg * 64 + wv * 16 + n;   // this lane's output column

  unsigned short* h0 = hbuf;
  unsigned short* h1 = hbuf + (size_t)NB * NH;
  unsigned int* flags = bar + bg * 32;        // one 128B line per batch-group

  // ---- resident B fragments: W_hh^T slice (bf16) in VGPRs ----
  short8 whh[32];
  #pragma unroll
  for (int kt = 0; kt < 32; ++kt){
    const float* p = W_hh + (size_t)j * NH + kt * 32 + quad * 8;
    float4v a = *(const float4v*)p;
    float4v b = *(const float4v*)(p + 4);
    short8 v;
    v[0]=(short)f2bf(a[0]); v[1]=(short)f2bf(a[1]); v[2]=(short)f2bf(a[2]); v[3]=(short)f2bf(a[3]);
    v[4]=(short)f2bf(b[0]); v[5]=(short)f2bf(b[1]); v[6]=(short)f2bf(b[2]); v[7]=(short)f2bf(b[3]);
    whh[kt] = v;
  }
  short8 wih[8];
  #pragma unroll
  for (int kt = 0; kt < 8; ++kt){
    short8 v = {0,0,0,0,0,0,0,0};
    if (!(kt == 7 && quad == 3)){            // k in [248,256) -> zero pad
      const float* p = W_ih + (size_t)j * NIN + kt * 32 + quad * 8;
      float4v a = *(const float4v*)p;
      float4v b = *(const float4v*)(p + 4);
      v[0]=(short)f2bf(a[0]); v[1]=(short)f2bf(a[1]); v[2]=(short)f2bf(a[2]); v[3]=(short)f2bf(a[3]);
      v[4]=(short)f2bf(b[0]); v[5]=(short)f2bf(b[1]); v[6]=(short)f2bf(b[2]); v[7]=(short)f2bf(b[3]);
    }
    wih[kt] = v;
  }
  const float bias  = b_ih[j] + b_hh[j];
  const float woutj = W_out[j];

  // ---- init: z_hist = 0, h0 slice = 0, z global slice = 0 ----
  #pragma unroll
  for (int i = 0; i < 32; ++i) z_hist[tid + i * 256] = 0.f;
  {
    int r = tid >> 4, c = (tid & 15) * 4;
    __hip_atomic_store((u64*)&h0[(size_t)(b_base + r) * NH + jg * 64 + c],
                       0ull, AS_RELAXED, AS_AGENT);
    int tt = jg * 32 + (tid >> 3);
    int bb = (tid & 7) * 2;
    __hip_atomic_store(&z[(size_t)tt * NB + b_base + bb],     0.f, AS_RELAXED, AS_AGENT);
    __hip_atomic_store(&z[(size_t)tt * NB + b_base + bb + 1], 0.f, AS_RELAXED, AS_AGENT);
  }

  // ---- x prefetch slots (t=0) ----
  const int xslot_kt[2] = { tid >> 6, (tid + 256) >> 6 };
  const int xslot_l2[2] = { tid & 63, tid & 63 };
  float4v xr[2][2];
  bool    xvalid[2];
  #pragma unroll
  for (int i = 0; i < 2; ++i){
    int kt = xslot_kt[i], l2 = xslot_l2[i];
    int b = b_base + (l2 & 15), k = kt * 32 + (l2 >> 4) * 8;
    xvalid[i] = !(kt == 7 && (l2 >> 4) == 3);
    if (xvalid[i]){
      const float* p = x + ((size_t)0 * NB + b) * NIN + k;
      xr[i][0] = *(const float4v*)p;
      xr[i][1] = *(const float4v*)(p + 4);
    }
  }

  // publish h[0] (init zeros): flag = 1
  __syncthreads();   // drains init stores (vmcnt(0) before s_barrier)
  if (tid == 0)
    __hip_atomic_store(&flags[jg], 1u, AS_RELAXED, AS_AGENT);

  for (int t = 0; t < T_SEQ; ++t){
    const unsigned short* hp = (t & 1) ? h1 : h0;
    unsigned short*       hn = (t & 1) ? h0 : h1;

    // wait (per-wave) for all 16 producers of h[t]: lanes 0..15 each watch
    // one flag word; single vector load per poll round, no RMW, no barrier.
    {
      const unsigned int tgt = (unsigned)(t + 1);
      const unsigned int* f = &flags[l & 15];
      while (__hip_atomic_load(f, AS_RELAXED, AS_AGENT) < tgt)
        __builtin_amdgcn_s_sleep(1);
    }

    // P1: issue ALL 16 coherent 8B loads first (max memory-level
    // parallelism), convert x while they are in flight, then LDS-write.
    u64 hw0[8], hw1[8];
    #pragma unroll
    for (int i = 0; i < 8; ++i){
      int slot = tid + i * 256;
      int kt = slot >> 6, l2 = slot & 63;
      int b = b_base + (l2 & 15), k = kt * 32 + (l2 >> 4) * 8;
      const u64* src = (const u64*)(hp + (size_t)b * NH + k);
      hw0[i] = __hip_atomic_load(src,     AS_RELAXED, AS_AGENT);
      hw1[i] = __hip_atomic_load(src + 1, AS_RELAXED, AS_AGENT);
    }
    #pragma unroll
    for (int i = 0; i < 2; ++i){
      int slot = tid + i * 256;
      uint4v v = {0u,0u,0u,0u};
      if (xvalid[i]){
        v[0] = (unsigned)f2bf(xr[i][0][0]) | ((unsigned)f2bf(xr[i][0][1]) << 16);
        v[1] = (unsigned)f2bf(xr[i][0][2]) | ((unsigned)f2bf(xr[i][0][3]) << 16);
        v[2] = (unsigned)f2bf(xr[i][1][0]) | ((unsigned)f2bf(xr[i][1][1]) << 16);
        v[3] = (unsigned)f2bf(xr[i][1][2]) | ((unsigned)f2bf(xr[i][1][3]) << 16);
      }
      *(uint4v*)&x_frag[slot * 8] = v;
    }
    #pragma unroll
    for (int i = 0; i < 8; ++i){
      u64* dst = (u64*)&h_frag[(tid + i * 256) * 8];
      dst[0] = hw0[i]; dst[1] = hw1[i];
    }
    __syncthreads();

    // P2: MFMA, FOUR independent accumulator chains (dep distance 4)
    f32x4 a0 = {bias, bias, bias, bias};
    f32x4 a1 = {0.f, 0.f, 0.f, 0.f};
    f32x4 a2 = {0.f, 0.f, 0.f, 0.f};
    f32x4 a3 = {0.f, 0.f, 0.f, 0.f};
    #pragma unroll
    for (int kt = 0; kt < 32; kt += 4){
      short8 f0 = *(const short8*)&h_frag[((kt + 0) * 64 + l) * 8];
      short8 f1 = *(const short8*)&h_frag[((kt + 1) * 64 + l) * 8];
      short8 f2 = *(const short8*)&h_frag[((kt + 2) * 64 + l) * 8];
      short8 f3 = *(const short8*)&h_frag[((kt + 3) * 64 + l) * 8];
      a0 = __builtin_amdgcn_mfma_f32_16x16x32_bf16(f0, whh[kt + 0], a0, 0, 0, 0);
      a1 = __builtin_amdgcn_mfma_f32_16x16x32_bf16(f1, whh[kt + 1], a1, 0, 0, 0);
      a2 = __builtin_amdgcn_mfma_f32_16x16x32_bf16(f2, whh[kt + 2], a2, 0, 0, 0);
      a3 = __builtin_amdgcn_mfma_f32_16x16x32_bf16(f3, whh[kt + 3], a3, 0, 0, 0);
    }
    #pragma unroll
    for (int kt = 0; kt < 8; kt += 4){
      short8 f0 = *(const short8*)&x_frag[((kt + 0) * 64 + l) * 8];
      short8 f1 = *(const short8*)&x_frag[((kt + 1) * 64 + l) * 8];
      short8 f2 = *(const short8*)&x_frag[((kt + 2) * 64 + l) * 8];
      short8 f3 = *(const short8*)&x_frag[((kt + 3) * 64 + l) * 8];
      a0 = __builtin_amdgcn_mfma_f32_16x16x32_bf16(f0, wih[kt + 0], a0, 0, 0, 0);
      a1 = __builtin_amdgcn_mfma_f32_16x16x32_bf16(f1, wih[kt + 1], a1, 0, 0, 0);
      a2 = __builtin_amdgcn_mfma_f32_16x16x32_bf16(f2, wih[kt + 2], a2, 0, 0, 0);
      a3 = __builtin_amdgcn_mfma_f32_16x16x32_bf16(f3, wih[kt + 3], a3, 0, 0, 0);
    }

    // prefetch x for t+1 (issues during MFMA drain; overlaps exchange)
    {
      int tn = (t + 1 < T_SEQ) ? t + 1 : t;
      #pragma unroll
      for (int i = 0; i < 2; ++i){
        if (xvalid[i]){
          int kt = xslot_kt[i], l2 = xslot_l2[i];
          int b = b_base + (l2 & 15), k = kt * 32 + (l2 >> 4) * 8;
          const float* p = x + ((size_t)tn * NB + b) * NIN + k;
          xr[i][0] = *(const float4v*)p;
          xr[i][1] = *(const float4v*)(p + 4);
        }
      }
    }

    // P3a: tanh + LDS transpose of h_new
    float hv[4];
    #pragma unroll
    for (int i = 0; i < 4; ++i){
      hv[i] = tanh_fast(a0[i] + a1[i] + a2[i] + a3[i]);
      // C/D layout: row(b) = quad*4 + i, col(j) = n
      h_out[(quad * 4 + i) * 64 + wv * 16 + n] = f2bf(hv[i]);
    }
    __syncthreads();

    // store h_new tile FIRST (one coherent 8B store per thread), then do
    // the z shuffle-reduce in the shadow of the store drain.
    {
      int r = tid >> 4, c = (tid & 15) * 4;
      u64 v = *(const u64*)&h_out[r * 64 + c];
      __hip_atomic_store((u64*)&hn[(size_t)(b_base + r) * NH + jg * 64 + c],
                         v, AS_RELAXED, AS_AGENT);
    }
    float sv[4];
    #pragma unroll
    for (int i = 0; i < 4; ++i) sv[i] = hv[i] * woutj;
    #pragma unroll
    for (int m = 1; m < 16; m <<= 1){
      #pragma unroll
      for (int i = 0; i < 4; ++i) sv[i] += __shfl_xor(sv[i], m, 64);
    }
    if (n == 0){
      #pragma unroll
      for (int i = 0; i < 4; ++i) atomicAdd(&z_hist[t * 16 + quad * 4 + i], sv[i]);
    }

    // drain all waves' h stores (vmcnt(0) before s_barrier), then publish
    __syncthreads();
    if (tid == 0)
      __hip_atomic_store(&flags[jg], (unsigned)(t + 2), AS_RELAXED, AS_AGENT);
  }

  // ---- bulk z flush (off the critical path) ----
  __syncthreads();
  #pragma unroll
  for (int i = 0; i < 32; ++i){
    int idx = tid + i * 256;
    int tt = idx >> 4, bb = idx & 15;
    atomicAdd(&z[(size_t)tt * NB + b_base + bb], z_hist[idx]);
  }
}

// o_t = sigmoid(z_t + b_out + w_r*o_{t-1} + b_r), o_0 = sigmoid(z_0 + b_out).
// 256 independent chains. Output (B, T) row-major.
__global__ void out_scan_kernel(const float* __restrict__ z,
                                const float* __restrict__ b_out,
                                const float* __restrict__ w_r,
                                const float* __restrict__ b_r,
                                float* __restrict__ out)
{
  int b = threadIdx.x;
  float bo = b_out[0], wr = w_r[0], br = b_r[0];
  float o = 0.f;
  for (int t = 0; t < T_SEQ; ++t){
    float pre = z[(size_t)t * NB + b] + bo;
    if (t > 0) pre += wr * o + br;
    o = 1.0f / (1.0f + __expf(-pre));
    out[(size_t)b * T_SEQ + t] = o;
  }
}

extern "C" void kernel_launch(void* const* d_in, const int* in_sizes, int n_in,
                              void* d_out, int out_size, void* d_ws, size_t ws_size,
                              hipStream_t stream)
{
  (void)in_sizes; (void)n_in; (void)out_size; (void)ws_size;
  const float* x     = (const float*)d_in[0];
  const float* W_ih  = (const float*)d_in[1];
  const float* b_ih  = (const float*)d_in[2];
  const float* W_hh  = (const float*)d_in[3];
  const float* b_hh  = (const float*)d_in[4];
  const float* W_out = (const float*)d_in[5];
  const float* b_out = (const float*)d_in[6];
  const float* w_r   = (const float*)d_in[7];
  const float* b_r   = (const float*)d_in[8];
  float* out = (float*)d_out;

  // ws: h ping-pong (2 x 512 KB bf16) | z (512 KB fp32) | flags (2 KB)
  unsigned short* hbuf = (unsigned short*)d_ws;
  float* z = (float*)((char*)d_ws + 2 * (size_t)NB * NH * sizeof(unsigned short));
  unsigned int* bar = (unsigned int*)((char*)d_ws
                        + 2 * (size_t)NB * NH * sizeof(unsigned short)
                        + (size_t)T_SEQ * NB * sizeof(float));

  hipMemsetAsync(bar, 0, 16 * 32 * sizeof(unsigned int), stream);

  rnn_scan_kernel<<<dim3(256), dim3(256), 0, stream>>>(
      x, W_ih, b_ih, W_hh, b_hh, W_out, hbuf, z, bar);

  out_scan_kernel<<<dim3(1), dim3(256), 0, stream>>>(z, b_out, w_r, b_r, out);
}